// Round 4
// baseline (337.638 us; speedup 1.0000x reference)
//
#include <hip/hip_runtime.h>
#include <hip/hip_bf16.h>

#define C_OUT 96
#define FEAT_DIM 48
#define HW 256
#define NPIX 65536          // 256*256
#define RES 65536           // rows in fa
#define IMG_C 3

typedef __attribute__((ext_vector_type(2))) float f32x2;
typedef __attribute__((ext_vector_type(4))) float f32x4;
typedef __attribute__((ext_vector_type(8))) unsigned short u16x8;
typedef __attribute__((ext_vector_type(4))) unsigned short u16x4;

static __device__ __forceinline__ unsigned short f2bf(float f) {
    // round-to-nearest-even f32 -> bf16
    unsigned u = __float_as_uint(f);
    u += 0x7fffu + ((u >> 16) & 1u);
    return (unsigned short)(u >> 16);
}
static __device__ __forceinline__ float bf2f(unsigned short h) {
    return __uint_as_float(((unsigned)h) << 16);
}

// ---------------------------------------------------------------------------
// Stage 1: 3x3 SAME conv (cross-correlation), NCHW. Each thread computes 4
// consecutive flat outputs and writes them as bf16 into the split tables:
//   flat f -> row r = f/96, col j = f%96;  j<48 -> FX[r][j], else FY[r][j-48]
// ---------------------------------------------------------------------------
__global__ __launch_bounds__(256) void conv_kernel(
    const float* __restrict__ img,          // [3,256,256]
    const float* __restrict__ w,            // [96,3,3,3]
    const float* __restrict__ b,            // [96]
    unsigned short* __restrict__ FX,        // [65536,48] bf16
    unsigned short* __restrict__ FY)        // [65536,48] bf16
{
    __shared__ float ws[C_OUT * 27];
    __shared__ float bs[C_OUT];
    for (int i = threadIdx.x; i < C_OUT * 27; i += blockDim.x) ws[i] = w[i];
    for (int i = threadIdx.x; i < C_OUT; i += blockDim.x) bs[i] = b[i];
    __syncthreads();

    int tid = blockIdx.x * blockDim.x + threadIdx.x;
    if (tid >= (C_OUT * NPIX) / 4) return;
    int f = tid << 2;                // flat output index of first of 4
    int c  = f >> 16;                // channel
    int p  = f & 65535;              // pixel
    int h  = p >> 8;
    int wc = p & 255;                // multiple of 4

    float a0 = bs[c], a1 = a0, a2 = a0, a3 = a0;
#pragma unroll
    for (int ci = 0; ci < IMG_C; ++ci) {
        const float* ip = img + ci * NPIX;
#pragma unroll
        for (int kh = 0; kh < 3; ++kh) {
            int hh = h + kh - 1;
            if ((unsigned)hh >= 256u) continue;
            const float* row = ip + hh * HW;
            float win[6];
#pragma unroll
            for (int k = 0; k < 6; ++k) {
                int ww = wc + k - 1;
                win[k] = ((unsigned)ww < 256u) ? row[ww] : 0.0f;
            }
            const float* wk = &ws[c * 27 + ci * 9 + kh * 3];
#pragma unroll
            for (int kw = 0; kw < 3; ++kw) {
                float wt = wk[kw];
                a0 = fmaf(win[kw + 0], wt, a0);
                a1 = fmaf(win[kw + 1], wt, a1);
                a2 = fmaf(win[kw + 2], wt, a2);
                a3 = fmaf(win[kw + 3], wt, a3);
            }
        }
    }

    int r = (unsigned)f / 96u;
    int j = f - r * 96;
    u16x4 pk;
    pk.x = f2bf(a0); pk.y = f2bf(a1); pk.z = f2bf(a2); pk.w = f2bf(a3);
    unsigned short* dst = (j < FEAT_DIM)
        ? (FX + (size_t)r * FEAT_DIM + j)
        : (FY + (size_t)r * FEAT_DIM + (j - FEAT_DIM));
    *(u16x4*)dst = pk;
}

// ---------------------------------------------------------------------------
// Stage 2: per-point dual 1-D interpolation gather from bf16 split tables.
// 3 threads per point; each thread owns 16 features: 2x16B loads from each of
// the 4 gathered rows (8 independent loads in flight), 4 f32x4 nt stores.
// ---------------------------------------------------------------------------
__global__ __launch_bounds__(256) void interp_kernel(
    const float* __restrict__ pts,            // [N,2]
    const unsigned short* __restrict__ FX,    // [65536,48] bf16
    const unsigned short* __restrict__ FY,    // [65536,48] bf16
    float* __restrict__ out,                  // [N,48] f32
    int npts)
{
    int t = blockIdx.x * blockDim.x + threadIdx.x;
    int pt = t / 3;
    int q  = t - pt * 3;          // 16-feature chunk: 0..2
    if (pt >= npts) return;

    f32x2 p = __builtin_nontemporal_load((const f32x2*)pts + pt);

    // reference: clip(p*(res-1), 0, res-1-1e-5); hi rounds to 65535.0f in f32
    float x = fminf(fmaxf(p.x * 65535.0f, 0.0f), 65535.0f);
    float y = fminf(fmaxf(p.y * 65535.0f, 0.0f), 65535.0f);

    int x1 = (int)x;              // floor (x >= 0)
    int y1 = (int)y;
    int x2 = min(x1 + 1, RES - 1);
    int y2 = min(y1 + 1, RES - 1);

    float xw1 = (float)x2 - x;
    float xw2 = x - (float)x1;
    float yw1 = (float)y2 - y;
    float yw2 = y - (float)y1;

    const unsigned short* ax1 = FX + (size_t)x1 * FEAT_DIM + q * 16;
    const unsigned short* ax2 = FX + (size_t)x2 * FEAT_DIM + q * 16;
    const unsigned short* ay1 = FY + (size_t)y1 * FEAT_DIM + q * 16;
    const unsigned short* ay2 = FY + (size_t)y2 * FEAT_DIM + q * 16;

    // 8 independent 16B gathers — all issued before any use
    u16x8 A0 = *(const u16x8*)(ax1);
    u16x8 A1 = *(const u16x8*)(ax1 + 8);
    u16x8 B0 = *(const u16x8*)(ax2);
    u16x8 B1 = *(const u16x8*)(ax2 + 8);
    u16x8 C0 = *(const u16x8*)(ay1);
    u16x8 C1 = *(const u16x8*)(ay1 + 8);
    u16x8 D0 = *(const u16x8*)(ay2);
    u16x8 D1 = *(const u16x8*)(ay2 + 8);

    float o[16];
#pragma unroll
    for (int k = 0; k < 8; ++k) {
        o[k] = xw1 * bf2f(A0[k]) + xw2 * bf2f(B0[k])
             + yw1 * bf2f(C0[k]) + yw2 * bf2f(D0[k]);
    }
#pragma unroll
    for (int k = 0; k < 8; ++k) {
        o[8 + k] = xw1 * bf2f(A1[k]) + xw2 * bf2f(B1[k])
                 + yw1 * bf2f(C1[k]) + yw2 * bf2f(D1[k]);
    }

    float* op = out + (size_t)pt * FEAT_DIM + q * 16;
    f32x4 v0 = {o[0],  o[1],  o[2],  o[3]};
    f32x4 v1 = {o[4],  o[5],  o[6],  o[7]};
    f32x4 v2 = {o[8],  o[9],  o[10], o[11]};
    f32x4 v3 = {o[12], o[13], o[14], o[15]};
    __builtin_nontemporal_store(v0, (f32x4*)op);
    __builtin_nontemporal_store(v1, (f32x4*)(op + 4));
    __builtin_nontemporal_store(v2, (f32x4*)(op + 8));
    __builtin_nontemporal_store(v3, (f32x4*)(op + 12));
}

extern "C" void kernel_launch(void* const* d_in, const int* in_sizes, int n_in,
                              void* d_out, int out_size, void* d_ws, size_t ws_size,
                              hipStream_t stream) {
    const float* pts    = (const float*)d_in[0];  // [N,2]
    const float* image  = (const float*)d_in[1];  // [1,3,256,256]
    const float* conv_w = (const float*)d_in[2];  // [96,3,3,3]
    const float* conv_b = (const float*)d_in[3];  // [96]
    float* out = (float*)d_out;                   // [N,48]

    unsigned short* FX = (unsigned short*)d_ws;               // 6.29 MB
    unsigned short* FY = FX + (size_t)RES * FEAT_DIM;         // 6.29 MB

    int npts = in_sizes[0] / 2;

    {
        int total = (C_OUT * NPIX) / 4;               // 1,572,864 threads
        int blocks = (total + 255) / 256;
        conv_kernel<<<blocks, 256, 0, stream>>>(image, conv_w, conv_b, FX, FY);
    }
    {
        long long total = (long long)npts * 3;
        int blocks = (int)((total + 255) / 256);
        interp_kernel<<<blocks, 256, 0, stream>>>(pts, FX, FY, out, npts);
    }
}

// Round 5
// 239.038 us; speedup vs baseline: 1.4125x; 1.4125x over previous
//
#include <hip/hip_runtime.h>
#include <hip/hip_bf16.h>

#define C_OUT 96
#define FEAT_DIM 48
#define HW 256
#define NPIX 65536          // 256*256
#define RES 65536           // rows in fa
#define IMG_C 3

typedef __attribute__((ext_vector_type(2))) float f32x2;
typedef __attribute__((ext_vector_type(4))) float f32x4;
typedef __attribute__((ext_vector_type(8))) unsigned short u16x8;
typedef __attribute__((ext_vector_type(4))) unsigned short u16x4;

static __device__ __forceinline__ unsigned short f2bf(float f) {
    // round-to-nearest-even f32 -> bf16
    unsigned u = __float_as_uint(f);
    u += 0x7fffu + ((u >> 16) & 1u);
    return (unsigned short)(u >> 16);
}
static __device__ __forceinline__ float bf2f(unsigned short h) {
    return __uint_as_float(((unsigned)h) << 16);
}

// ---------------------------------------------------------------------------
// Stage 1: 3x3 SAME conv (cross-correlation), NCHW. Each thread computes 4
// consecutive flat outputs and writes them as bf16 into the split tables:
//   flat f -> row r = f/96, col j = f%96;  j<48 -> FX[r][j], else FY[r][j-48]
// ---------------------------------------------------------------------------
__global__ __launch_bounds__(256) void conv_kernel(
    const float* __restrict__ img,          // [3,256,256]
    const float* __restrict__ w,            // [96,3,3,3]
    const float* __restrict__ b,            // [96]
    unsigned short* __restrict__ FX,        // [65536,48] bf16
    unsigned short* __restrict__ FY)        // [65536,48] bf16
{
    __shared__ float ws[C_OUT * 27];
    __shared__ float bs[C_OUT];
    for (int i = threadIdx.x; i < C_OUT * 27; i += blockDim.x) ws[i] = w[i];
    for (int i = threadIdx.x; i < C_OUT; i += blockDim.x) bs[i] = b[i];
    __syncthreads();

    int tid = blockIdx.x * blockDim.x + threadIdx.x;
    if (tid >= (C_OUT * NPIX) / 4) return;
    int f = tid << 2;                // flat output index of first of 4
    int c  = f >> 16;                // channel
    int p  = f & 65535;              // pixel
    int h  = p >> 8;
    int wc = p & 255;                // multiple of 4

    float a0 = bs[c], a1 = a0, a2 = a0, a3 = a0;
#pragma unroll
    for (int ci = 0; ci < IMG_C; ++ci) {
        const float* ip = img + ci * NPIX;
#pragma unroll
        for (int kh = 0; kh < 3; ++kh) {
            int hh = h + kh - 1;
            if ((unsigned)hh >= 256u) continue;
            const float* row = ip + hh * HW;
            float win[6];
#pragma unroll
            for (int k = 0; k < 6; ++k) {
                int ww = wc + k - 1;
                win[k] = ((unsigned)ww < 256u) ? row[ww] : 0.0f;
            }
            const float* wk = &ws[c * 27 + ci * 9 + kh * 3];
#pragma unroll
            for (int kw = 0; kw < 3; ++kw) {
                float wt = wk[kw];
                a0 = fmaf(win[kw + 0], wt, a0);
                a1 = fmaf(win[kw + 1], wt, a1);
                a2 = fmaf(win[kw + 2], wt, a2);
                a3 = fmaf(win[kw + 3], wt, a3);
            }
        }
    }

    int r = (unsigned)f / 96u;
    int j = f - r * 96;
    u16x4 pk;
    pk.x = f2bf(a0); pk.y = f2bf(a1); pk.z = f2bf(a2); pk.w = f2bf(a3);
    unsigned short* dst = (j < FEAT_DIM)
        ? (FX + (size_t)r * FEAT_DIM + j)
        : (FY + (size_t)r * FEAT_DIM + (j - FEAT_DIM));
    *(u16x4*)dst = pk;
}

// ---------------------------------------------------------------------------
// Stage 2: dual 1-D interpolation gather from bf16 split tables.
// Round-2 memory shape (6 lanes per point, u16x8 = contiguous 96B span per
// point per load instruction), but TWO points per thread so 8 independent
// gathers are in flight per thread (double the MLP of Round 2 at the same
// wave-level coalescing).
// ---------------------------------------------------------------------------
__global__ __launch_bounds__(256) void interp_kernel(
    const float* __restrict__ pts,            // [N,2]
    const unsigned short* __restrict__ FX,    // [65536,48] bf16
    const unsigned short* __restrict__ FY,    // [65536,48] bf16
    float* __restrict__ out,                  // [N,48] f32
    int npts)
{
    int t = blockIdx.x * blockDim.x + threadIdx.x;
    int g = t / 6;                 // point-pair index
    int q = t - g * 6;             // 8-feature chunk: 0..5
    int p0 = 2 * g;
    if (p0 >= npts) return;
    int p1 = p0 + 1;
    bool has1 = (p1 < npts);

    f32x4 P;
    if (has1) {
        P = *((const f32x4*)pts + g);        // both points, one 16B load
    } else {
        f32x2 v = *((const f32x2*)pts + p0);
        P.x = v.x; P.y = v.y; P.z = v.x; P.w = v.y;
    }

    // reference: clip(p*(res-1), 0, res-1-1e-5); hi rounds to 65535.0f in f32
    float xa = fminf(fmaxf(P.x * 65535.0f, 0.0f), 65535.0f);
    float ya = fminf(fmaxf(P.y * 65535.0f, 0.0f), 65535.0f);
    float xb = fminf(fmaxf(P.z * 65535.0f, 0.0f), 65535.0f);
    float yb = fminf(fmaxf(P.w * 65535.0f, 0.0f), 65535.0f);

    int x1a = (int)xa, y1a = (int)ya, x1b = (int)xb, y1b = (int)yb;
    int x2a = min(x1a + 1, RES - 1), y2a = min(y1a + 1, RES - 1);
    int x2b = min(x1b + 1, RES - 1), y2b = min(y1b + 1, RES - 1);

    float xw1a = (float)x2a - xa, xw2a = xa - (float)x1a;
    float yw1a = (float)y2a - ya, yw2a = ya - (float)y1a;
    float xw1b = (float)x2b - xb, xw2b = xb - (float)x1b;
    float yw1b = (float)y2b - yb, yw2b = yb - (float)y1b;

    int qo = q * 8;
    // 8 independent 16B gathers — all issued before any use
    const u16x8 Aa = *(const u16x8*)(FX + (size_t)x1a * FEAT_DIM + qo);
    const u16x8 Ba = *(const u16x8*)(FX + (size_t)x2a * FEAT_DIM + qo);
    const u16x8 Ca = *(const u16x8*)(FY + (size_t)y1a * FEAT_DIM + qo);
    const u16x8 Da = *(const u16x8*)(FY + (size_t)y2a * FEAT_DIM + qo);
    const u16x8 Ab = *(const u16x8*)(FX + (size_t)x1b * FEAT_DIM + qo);
    const u16x8 Bb = *(const u16x8*)(FX + (size_t)x2b * FEAT_DIM + qo);
    const u16x8 Cb = *(const u16x8*)(FY + (size_t)y1b * FEAT_DIM + qo);
    const u16x8 Db = *(const u16x8*)(FY + (size_t)y2b * FEAT_DIM + qo);

    float oa[8], ob[8];
#pragma unroll
    for (int k = 0; k < 8; ++k) {
        oa[k] = xw1a * bf2f(Aa[k]) + xw2a * bf2f(Ba[k])
              + yw1a * bf2f(Ca[k]) + yw2a * bf2f(Da[k]);
    }
#pragma unroll
    for (int k = 0; k < 8; ++k) {
        ob[k] = xw1b * bf2f(Ab[k]) + xw2b * bf2f(Bb[k])
              + yw1b * bf2f(Cb[k]) + yw2b * bf2f(Db[k]);
    }

    float* op0 = out + (size_t)p0 * FEAT_DIM + qo;
    f32x4 v0 = {oa[0], oa[1], oa[2], oa[3]};
    f32x4 v1 = {oa[4], oa[5], oa[6], oa[7]};
    __builtin_nontemporal_store(v0, (f32x4*)op0);
    __builtin_nontemporal_store(v1, (f32x4*)(op0 + 4));

    if (has1) {
        float* op1 = out + (size_t)p1 * FEAT_DIM + qo;
        f32x4 v2 = {ob[0], ob[1], ob[2], ob[3]};
        f32x4 v3 = {ob[4], ob[5], ob[6], ob[7]};
        __builtin_nontemporal_store(v2, (f32x4*)op1);
        __builtin_nontemporal_store(v3, (f32x4*)(op1 + 4));
    }
}

extern "C" void kernel_launch(void* const* d_in, const int* in_sizes, int n_in,
                              void* d_out, int out_size, void* d_ws, size_t ws_size,
                              hipStream_t stream) {
    const float* pts    = (const float*)d_in[0];  // [N,2]
    const float* image  = (const float*)d_in[1];  // [1,3,256,256]
    const float* conv_w = (const float*)d_in[2];  // [96,3,3,3]
    const float* conv_b = (const float*)d_in[3];  // [96]
    float* out = (float*)d_out;                   // [N,48]

    unsigned short* FX = (unsigned short*)d_ws;               // 6.29 MB
    unsigned short* FY = FX + (size_t)RES * FEAT_DIM;         // 6.29 MB

    int npts = in_sizes[0] / 2;

    {
        int total = (C_OUT * NPIX) / 4;               // 1,572,864 threads
        int blocks = (total + 255) / 256;
        conv_kernel<<<blocks, 256, 0, stream>>>(image, conv_w, conv_b, FX, FY);
    }
    {
        long long npairs = (npts + 1) / 2;
        long long total = npairs * 6;
        int blocks = (int)((total + 255) / 256);
        interp_kernel<<<blocks, 256, 0, stream>>>(pts, FX, FY, out, npts);
    }
}

// Round 6
// 236.189 us; speedup vs baseline: 1.4295x; 1.0121x over previous
//
#include <hip/hip_runtime.h>
#include <hip/hip_bf16.h>

#define C_OUT 96
#define FEAT_DIM 48
#define HW 256
#define NPIX 65536          // 256*256
#define RES 65536           // rows in fa
#define IMG_C 3
#define NBUCKET 256         // 16 x-slices * 16 y-slices
#define SCAT_PPT 8          // points per thread in scatter

typedef __attribute__((ext_vector_type(2))) float f32x2;
typedef __attribute__((ext_vector_type(4))) float f32x4;
typedef __attribute__((ext_vector_type(8))) unsigned short u16x8;
typedef __attribute__((ext_vector_type(4))) unsigned short u16x4;

static __device__ __forceinline__ unsigned short f2bf(float f) {
    unsigned u = __float_as_uint(f);
    u += 0x7fffu + ((u >> 16) & 1u);
    return (unsigned short)(u >> 16);
}
static __device__ __forceinline__ float bf2f(unsigned short h) {
    return __uint_as_float(((unsigned)h) << 16);
}
// reference: clip(p*(res-1), 0, res-1-1e-5); hi rounds to 65535.0f in f32
static __device__ __forceinline__ float clipcoord(float p) {
    return fminf(fmaxf(p * 65535.0f, 0.0f), 65535.0f);
}
static __device__ __forceinline__ int bkey(float x, float y) {
    int x1 = (int)x, y1 = (int)y;
    return ((x1 >> 12) << 4) | (y1 >> 12);   // kx-major
}

// ---------------------------------------------------------------------------
// Stage 1: 3x3 SAME conv -> bf16 split tables FX/FY (same as Round 2).
// ---------------------------------------------------------------------------
__global__ __launch_bounds__(256) void conv_kernel(
    const float* __restrict__ img, const float* __restrict__ w,
    const float* __restrict__ b,
    unsigned short* __restrict__ FX, unsigned short* __restrict__ FY)
{
    __shared__ float ws[C_OUT * 27];
    __shared__ float bs[C_OUT];
    for (int i = threadIdx.x; i < C_OUT * 27; i += blockDim.x) ws[i] = w[i];
    for (int i = threadIdx.x; i < C_OUT; i += blockDim.x) bs[i] = b[i];
    __syncthreads();

    int tid = blockIdx.x * blockDim.x + threadIdx.x;
    if (tid >= (C_OUT * NPIX) / 4) return;
    int f = tid << 2;
    int c  = f >> 16;
    int p  = f & 65535;
    int h  = p >> 8;
    int wc = p & 255;

    float a0 = bs[c], a1 = a0, a2 = a0, a3 = a0;
#pragma unroll
    for (int ci = 0; ci < IMG_C; ++ci) {
        const float* ip = img + ci * NPIX;
#pragma unroll
        for (int kh = 0; kh < 3; ++kh) {
            int hh = h + kh - 1;
            if ((unsigned)hh >= 256u) continue;
            const float* row = ip + hh * HW;
            float win[6];
#pragma unroll
            for (int k = 0; k < 6; ++k) {
                int ww = wc + k - 1;
                win[k] = ((unsigned)ww < 256u) ? row[ww] : 0.0f;
            }
            const float* wk = &ws[c * 27 + ci * 9 + kh * 3];
#pragma unroll
            for (int kw = 0; kw < 3; ++kw) {
                float wt = wk[kw];
                a0 = fmaf(win[kw + 0], wt, a0);
                a1 = fmaf(win[kw + 1], wt, a1);
                a2 = fmaf(win[kw + 2], wt, a2);
                a3 = fmaf(win[kw + 3], wt, a3);
            }
        }
    }

    int r = (unsigned)f / 96u;
    int j = f - r * 96;
    u16x4 pk;
    pk.x = f2bf(a0); pk.y = f2bf(a1); pk.z = f2bf(a2); pk.w = f2bf(a3);
    unsigned short* dst = (j < FEAT_DIM)
        ? (FX + (size_t)r * FEAT_DIM + j)
        : (FY + (size_t)r * FEAT_DIM + (j - FEAT_DIM));
    *(u16x4*)dst = pk;
}

// ---------------------------------------------------------------------------
// Sort pass A: per-block LDS histogram of bucket keys -> global hist.
// ---------------------------------------------------------------------------
__global__ __launch_bounds__(256) void hist_kernel(
    const float* __restrict__ pts, unsigned* __restrict__ hist, int npts)
{
    __shared__ unsigned lh[NBUCKET];
    for (int i = threadIdx.x; i < NBUCKET; i += blockDim.x) lh[i] = 0;
    __syncthreads();
    int stride = gridDim.x * blockDim.x;
    for (int i = blockIdx.x * blockDim.x + threadIdx.x; i < npts; i += stride) {
        f32x2 p = *((const f32x2*)pts + i);
        atomicAdd(&lh[bkey(clipcoord(p.x), clipcoord(p.y))], 1u);
    }
    __syncthreads();
    for (int i = threadIdx.x; i < NBUCKET; i += blockDim.x)
        if (lh[i]) atomicAdd(&hist[i], lh[i]);
}

// ---------------------------------------------------------------------------
// Sort pass B: exclusive prefix sum of hist -> cursor (single block, 256 thr).
// ---------------------------------------------------------------------------
__global__ __launch_bounds__(256) void scan_kernel(
    const unsigned* __restrict__ hist, unsigned* __restrict__ cursor)
{
    __shared__ unsigned tmp[NBUCKET];
    int t = threadIdx.x;
    unsigned own = hist[t];
    tmp[t] = own;
    __syncthreads();
#pragma unroll
    for (int off = 1; off < NBUCKET; off <<= 1) {
        unsigned v = (t >= off) ? tmp[t - off] : 0u;
        __syncthreads();
        tmp[t] += v;
        __syncthreads();
    }
    cursor[t] = tmp[t] - own;   // exclusive
}

// ---------------------------------------------------------------------------
// Sort pass C: scatter points into bucket-sorted array of {x,y,idx,pad}.
// Per-block reservation (one global atomic per bucket per block).
// ---------------------------------------------------------------------------
__global__ __launch_bounds__(256) void scatter_kernel(
    const float* __restrict__ pts, unsigned* __restrict__ cursor,
    f32x4* __restrict__ sorted, int npts)
{
    __shared__ unsigned lh[NBUCKET];
    __shared__ unsigned lbase[NBUCKET];
    int t = threadIdx.x;
    for (int i = t; i < NBUCKET; i += blockDim.x) lh[i] = 0;
    __syncthreads();

    int start = blockIdx.x * (blockDim.x * SCAT_PPT);
    float xs[SCAT_PPT], ys[SCAT_PPT];
    int keys[SCAT_PPT];
#pragma unroll
    for (int k = 0; k < SCAT_PPT; ++k) {
        int i = start + k * blockDim.x + t;
        if (i < npts) {
            f32x2 p = *((const f32x2*)pts + i);
            xs[k] = clipcoord(p.x);
            ys[k] = clipcoord(p.y);
            keys[k] = bkey(xs[k], ys[k]);
            atomicAdd(&lh[keys[k]], 1u);
        } else keys[k] = -1;
    }
    __syncthreads();
    for (int i = t; i < NBUCKET; i += blockDim.x)
        lbase[i] = lh[i] ? atomicAdd(&cursor[i], lh[i]) : 0u;
    __syncthreads();
    for (int i = t; i < NBUCKET; i += blockDim.x) lh[i] = 0;
    __syncthreads();
#pragma unroll
    for (int k = 0; k < SCAT_PPT; ++k) {
        if (keys[k] >= 0) {
            unsigned slot = lbase[keys[k]] + atomicAdd(&lh[keys[k]], 1u);
            int i = start + k * blockDim.x + t;
            f32x4 rec;
            rec.x = xs[k]; rec.y = ys[k];
            rec.z = __uint_as_float((unsigned)i); rec.w = 0.0f;
            sorted[slot] = rec;
        }
    }
}

// ---------------------------------------------------------------------------
// Stage 2: interp over bucket-sorted points (Round-2 memory shape: 6 lanes
// per point, u16x8 row loads). XCD-bijective block swizzle (m204) so each XCD
// walks a contiguous 1/8 of the sorted array -> gather working set ~0.8MB/XCD
// stays L2-resident. Output written to original point index (192B/point).
// ---------------------------------------------------------------------------
__global__ __launch_bounds__(256) void interp_kernel(
    const f32x4* __restrict__ sorted,
    const unsigned short* __restrict__ FX,
    const unsigned short* __restrict__ FY,
    float* __restrict__ out, int npts, int nblk)
{
    // bijective XCD swizzle: orig -> contiguous chunk per XCD
    int orig = blockIdx.x;
    int xcd = orig & 7;
    int q8 = nblk >> 3, r8 = nblk & 7;
    int base = (xcd < r8) ? xcd * (q8 + 1) : r8 * (q8 + 1) + (xcd - r8) * q8;
    int sbid = base + (orig >> 3);

    int t = sbid * blockDim.x + threadIdx.x;
    int s = t / 6;
    int q = t - s * 6;            // 8-feature chunk: 0..5
    if (s >= npts) return;

    f32x4 rec = sorted[s];
    float x = rec.x, y = rec.y;
    unsigned idx = __float_as_uint(rec.z);

    int x1 = (int)x;
    int y1 = (int)y;
    int x2 = min(x1 + 1, RES - 1);
    int y2 = min(y1 + 1, RES - 1);

    float xw1 = (float)x2 - x;
    float xw2 = x - (float)x1;
    float yw1 = (float)y2 - y;
    float yw2 = y - (float)y1;

    int qo = q * 8;
    const u16x8 A = *(const u16x8*)(FX + (size_t)x1 * FEAT_DIM + qo);
    const u16x8 B = *(const u16x8*)(FX + (size_t)x2 * FEAT_DIM + qo);
    const u16x8 C = *(const u16x8*)(FY + (size_t)y1 * FEAT_DIM + qo);
    const u16x8 D = *(const u16x8*)(FY + (size_t)y2 * FEAT_DIM + qo);

    float o[8];
#pragma unroll
    for (int k = 0; k < 8; ++k) {
        o[k] = xw1 * bf2f(A[k]) + xw2 * bf2f(B[k])
             + yw1 * bf2f(C[k]) + yw2 * bf2f(D[k]);
    }

    float* op = out + (size_t)idx * FEAT_DIM + qo;
    f32x4 v0 = {o[0], o[1], o[2], o[3]};
    f32x4 v1 = {o[4], o[5], o[6], o[7]};
    __builtin_nontemporal_store(v0, (f32x4*)op);
    __builtin_nontemporal_store(v1, (f32x4*)(op + 4));
}

extern "C" void kernel_launch(void* const* d_in, const int* in_sizes, int n_in,
                              void* d_out, int out_size, void* d_ws, size_t ws_size,
                              hipStream_t stream) {
    const float* pts    = (const float*)d_in[0];
    const float* image  = (const float*)d_in[1];
    const float* conv_w = (const float*)d_in[2];
    const float* conv_b = (const float*)d_in[3];
    float* out = (float*)d_out;

    int npts = in_sizes[0] / 2;

    // ws layout: sorted (npts*16B) | FX (6.29MB) | FY (6.29MB) | hist | cursor
    char* wsb = (char*)d_ws;
    f32x4* sorted = (f32x4*)wsb;
    size_t sorted_bytes = ((size_t)npts * 16 + 255) & ~(size_t)255;
    unsigned short* FX = (unsigned short*)(wsb + sorted_bytes);
    unsigned short* FY = FX + (size_t)RES * FEAT_DIM;
    unsigned* hist   = (unsigned*)(wsb + sorted_bytes + 2 * (size_t)RES * FEAT_DIM * 2);
    unsigned* cursor = hist + NBUCKET;

    // zero histogram (cursor is fully written by scan_kernel)
    hipMemsetAsync(hist, 0, NBUCKET * sizeof(unsigned), stream);

    {
        int total = (C_OUT * NPIX) / 4;
        conv_kernel<<<(total + 255) / 256, 256, 0, stream>>>(image, conv_w, conv_b, FX, FY);
    }
    hist_kernel<<<1024, 256, 0, stream>>>(pts, hist, npts);
    scan_kernel<<<1, 256, 0, stream>>>(hist, cursor);
    {
        int per_block = 256 * SCAT_PPT;
        int blocks = (npts + per_block - 1) / per_block;
        scatter_kernel<<<blocks, 256, 0, stream>>>(pts, cursor, sorted, npts);
    }
    {
        long long total = (long long)npts * 6;
        int nblk = (int)((total + 255) / 256);
        interp_kernel<<<nblk, 256, 0, stream>>>(sorted, FX, FY, out, npts, nblk);
    }
}